// Round 7
// baseline (252.662 us; speedup 1.0000x reference)
//
#include <hip/hip_runtime.h>
#include <hip/hip_fp16.h>

#define B_ 4
#define S_ 2048
#define H_ 1024
#define M_ (B_ * S_)  // 8192 flattened rows of x / q / k / v

typedef _Float16 f16;
typedef _Float16 f16x8 __attribute__((ext_vector_type(8)));
typedef _Float16 f16x4 __attribute__((ext_vector_type(4)));
typedef float f32x4 __attribute__((ext_vector_type(4)));

typedef __attribute__((address_space(3))) unsigned int* lds_u32p;
typedef const __attribute__((address_space(1))) unsigned int* gbl_u32p;

// async global->LDS, 16B per lane; LDS dest is wave-uniform base + lane*16
__device__ __forceinline__ void stage16(const f16* g, f16* l) {
  __builtin_amdgcn_global_load_lds((gbl_u32p)g, (lds_u32p)l, 16, 0, 0);
}

// ---------------------------------------------------------------------------
// One launch: x (8192 blocks) then Wq/Wk/Wv (1024 blocks each) -> fp16 RNE.
__global__ __launch_bounds__(256) void downconvert_all(
    const float* __restrict__ x, const float* __restrict__ W0,
    const float* __restrict__ W1, const float* __restrict__ W2,
    f16* __restrict__ xh, f16* __restrict__ Wh) {
  const int b = blockIdx.x;
  const float* src;
  f16* dst;
  long i;
  if (b < M_ * H_ / 1024) {  // 8192 x-blocks
    src = x; dst = xh;
    i = (long)b * 256 + threadIdx.x;
  } else {
    const int wb = b - M_ * H_ / 1024;
    const int sel = wb >> 10;               // 1024 blocks per W
    src = sel == 0 ? W0 : (sel == 1 ? W1 : W2);
    dst = Wh + (long)sel * H_ * H_;
    i = (long)(wb & 1023) * 256 + threadIdx.x;
  }
  f32x4 v = ((const f32x4*)src)[i];
  f16x4 h;
#pragma unroll
  for (int c = 0; c < 4; c++) h[c] = (f16)v[c];
  ((f16x4*)dst)[i] = h;
}

// ---------------------------------------------------------------------------
// Fused QKV projection — round-0 structure VERBATIM (best measured: 61.5us).
// NOTE r6 lesson: do NOT add the chunk-XOR swizzle here — the pre-swizzled
// global source breaks global_load_lds lane coalescing (qkv 61.5 -> ~71us)
// while the conflicts it removes are already hidden at 2-phase.
// NT GEMM, 128x128 tile, BK=64 as two BK=32 sub-chunks per barrier.
// sel==2 (V) is written TRANSPOSED to vT[b][h][t].
__global__ __launch_bounds__(256, 2)
void qkv_gemm(const f16* __restrict__ xh, const f16* __restrict__ Wh,
              const float* __restrict__ bq, const float* __restrict__ bk,
              const float* __restrict__ bv, f16* __restrict__ qkv,
              f16* __restrict__ vT) {
  __shared__ __align__(16) f16 As[2 * 128 * 32];  // [chunk0 | chunk1]
  __shared__ __align__(16) f16 Bs[2 * 128 * 32];
  const int t = threadIdx.x;
  const int wave = t >> 6, lane = t & 63;
  const int quad = lane >> 4, l16 = lane & 15;
  const int wm = (wave & 1) * 64, wn = (wave >> 1) * 64;
  const int sel = blockIdx.y >> 3;             // 0=q 1=k 2=v
  const int ntile = (blockIdx.y & 7) * 128;
  const int mtile = blockIdx.x * 128;

  const f16* Ab = xh + (long)mtile * H_;
  const f16* Bb = Wh + (long)sel * H_ * H_ + (long)ntile * H_;

  const int r0 = t >> 2;        // staging row 0..63
  const int c8 = (t & 3) * 8;   // staging col (halfs)

  f32x4 acc[4][4] = {};

  for (int k0 = 0; k0 < H_; k0 += 64) {
    __syncthreads();
    stage16(Ab + (long)r0 * H_ + k0 + c8,             As + t * 8);
    stage16(Ab + (long)(r0 + 64) * H_ + k0 + c8,      As + 2048 + t * 8);
    stage16(Ab + (long)r0 * H_ + k0 + 32 + c8,        As + 4096 + t * 8);
    stage16(Ab + (long)(r0 + 64) * H_ + k0 + 32 + c8, As + 6144 + t * 8);
    stage16(Bb + (long)r0 * H_ + k0 + c8,             Bs + t * 8);
    stage16(Bb + (long)(r0 + 64) * H_ + k0 + c8,      Bs + 2048 + t * 8);
    stage16(Bb + (long)r0 * H_ + k0 + 32 + c8,        Bs + 4096 + t * 8);
    stage16(Bb + (long)(r0 + 64) * H_ + k0 + 32 + c8, Bs + 6144 + t * 8);
    __syncthreads();
#pragma unroll
    for (int kk = 0; kk < 2; kk++) {
      f16x8 ah[4], bh[4];
#pragma unroll
      for (int i = 0; i < 4; i++) {
        ah[i] = *(const f16x8*)&As[kk * 4096 + (wm + i * 16 + l16) * 32 + quad * 8];
        bh[i] = *(const f16x8*)&Bs[kk * 4096 + (wn + i * 16 + l16) * 32 + quad * 8];
      }
#pragma unroll
      for (int i = 0; i < 4; i++)
#pragma unroll
        for (int j = 0; j < 4; j++)
          acc[i][j] = __builtin_amdgcn_mfma_f32_16x16x32_f16(ah[i], bh[j], acc[i][j], 0, 0, 0);
    }
  }

  const float* bias = sel == 0 ? bq : (sel == 1 ? bk : bv);
  if (sel == 2) {
    // V transposed: vT[(b*H + n)*S + t_pos], b = m>>11, t_pos = m&2047.
#pragma unroll
    for (int j = 0; j < 4; j++) {
      int n = ntile + wn + j * 16 + l16;
      float bb = bias[n];
#pragma unroll
      for (int i = 0; i < 4; i++) {
        int m = mtile + wm + i * 16 + quad * 4;
        f16x4 pack;
#pragma unroll
        for (int r = 0; r < 4; r++) pack[r] = (f16)(acc[i][j][r] + bb);
        *(f16x4*)&vT[((long)(m >> 11) * H_ + n) * S_ + (m & 2047)] = pack;
      }
    }
  } else {
    f16* out = qkv + (long)sel * M_ * H_;
#pragma unroll
    for (int j = 0; j < 4; j++) {
      int n = ntile + wn + j * 16 + l16;
      float bb = bias[n];
#pragma unroll
      for (int i = 0; i < 4; i++) {
        int m = mtile + wm + i * 16 + quad * 4;
#pragma unroll
        for (int r = 0; r < 4; r++)
          out[(long)(m + r) * H_ + n] = (f16)(acc[i][j][r] + bb);
      }
    }
  }
}

// ---------------------------------------------------------------------------
// Generic batched NT fp16 GEMM — round-0 structure VERBATIM (no swizzle).
// C[z][m][n] = alpha * sum_k A[z][m][k]*B[z][n][k]
template <int OUT_F16>
__global__ __launch_bounds__(256, 2)
void gemm_nt(const f16* __restrict__ A, const f16* __restrict__ Bm,
             void* __restrict__ C, int lda, int ldb, int ldc, int K,
             long sA, long sB, long sC, float alpha) {
  __shared__ __align__(16) f16 As[2 * 128 * 32];
  __shared__ __align__(16) f16 Bs[2 * 128 * 32];
  const int t = threadIdx.x;
  const int wave = t >> 6, lane = t & 63;
  const int quad = lane >> 4, l16 = lane & 15;
  const int wm = (wave & 1) * 64, wn = (wave >> 1) * 64;
  const f16* Ab = A + blockIdx.z * sA + (long)blockIdx.x * 128 * lda;
  const f16* Bb = Bm + blockIdx.z * sB + (long)blockIdx.y * 128 * ldb;
  const int r0 = t >> 2, c8 = (t & 3) * 8;
  f32x4 acc[4][4] = {};
  for (int k0 = 0; k0 < K; k0 += 64) {
    __syncthreads();
    stage16(Ab + (long)r0 * lda + k0 + c8,             As + t * 8);
    stage16(Ab + (long)(r0 + 64) * lda + k0 + c8,      As + 2048 + t * 8);
    stage16(Ab + (long)r0 * lda + k0 + 32 + c8,        As + 4096 + t * 8);
    stage16(Ab + (long)(r0 + 64) * lda + k0 + 32 + c8, As + 6144 + t * 8);
    stage16(Bb + (long)r0 * ldb + k0 + c8,             Bs + t * 8);
    stage16(Bb + (long)(r0 + 64) * ldb + k0 + c8,      Bs + 2048 + t * 8);
    stage16(Bb + (long)r0 * ldb + k0 + 32 + c8,        Bs + 4096 + t * 8);
    stage16(Bb + (long)(r0 + 64) * ldb + k0 + 32 + c8, Bs + 6144 + t * 8);
    __syncthreads();
#pragma unroll
    for (int kk = 0; kk < 2; kk++) {
      f16x8 af[4], bf[4];
#pragma unroll
      for (int i = 0; i < 4; i++) {
        af[i] = *(const f16x8*)&As[kk * 4096 + (wm + i * 16 + l16) * 32 + quad * 8];
        bf[i] = *(const f16x8*)&Bs[kk * 4096 + (wn + i * 16 + l16) * 32 + quad * 8];
      }
#pragma unroll
      for (int i = 0; i < 4; i++)
#pragma unroll
        for (int j = 0; j < 4; j++)
          acc[i][j] = __builtin_amdgcn_mfma_f32_16x16x32_f16(af[i], bf[j], acc[i][j], 0, 0, 0);
    }
  }
  const long mb = (long)blockIdx.x * 128 + wm;
  const long nb = (long)blockIdx.y * 128 + wn;
#pragma unroll
  for (int i = 0; i < 4; i++)
#pragma unroll
    for (int j = 0; j < 4; j++) {
      long m = mb + i * 16 + quad * 4;
      long n = nb + j * 16 + l16;
#pragma unroll
      for (int r = 0; r < 4; r++) {
        float v = acc[i][j][r] * alpha;
        if (OUT_F16)
          ((f16*)C)[blockIdx.z * sC + (m + r) * ldc + n] = (f16)v;
        else
          ((float*)C)[blockIdx.z * sC + (m + r) * ldc + n] = v;
      }
    }
}

// ---------------------------------------------------------------------------
// Wave-per-row softmax + fp16 quantize: 4 rows per 256-thread block.
// No LDS, no __syncthreads, pure shfl reductions; 64B/lane vectorized I/O.
// (r6 WIN: replaced the 2-sync block-reduce version, ~15-25us total saving.)
__global__ __launch_bounds__(256) void softmax_w(f16* __restrict__ sc) {
  const int wave = threadIdx.x >> 6, lane = threadIdx.x & 63;
  const long row = (long)blockIdx.x * 4 + wave;
  f16* p = sc + row * S_;
  f16x8 v[4];
#pragma unroll
  for (int i = 0; i < 4; ++i) v[i] = ((const f16x8*)p)[i * 64 + lane];
  float f[32];
  float m = -3.0e38f;
#pragma unroll
  for (int i = 0; i < 4; ++i)
#pragma unroll
    for (int c = 0; c < 8; ++c) {
      float x = (float)v[i][c];
      f[i * 8 + c] = x;
      m = fmaxf(m, x);
    }
#pragma unroll
  for (int o = 32; o > 0; o >>= 1) m = fmaxf(m, __shfl_xor(m, o));
  float s = 0.f;
#pragma unroll
  for (int i = 0; i < 32; ++i) { f[i] = __expf(f[i] - m); s += f[i]; }
#pragma unroll
  for (int o = 32; o > 0; o >>= 1) s += __shfl_xor(s, o);
  const float inv = 1.0f / s;
#pragma unroll
  for (int i = 0; i < 4; ++i) {
    f16x8 ov;
#pragma unroll
    for (int c = 0; c < 8; ++c) ov[c] = (f16)(f[i * 8 + c] * inv);
    ((f16x8*)p)[i * 64 + lane] = ov;
  }
}

// ---------------------------------------------------------------------------
extern "C" void kernel_launch(void* const* d_in, const int* in_sizes, int n_in,
                              void* d_out, int out_size, void* d_ws, size_t ws_size,
                              hipStream_t stream) {
  (void)in_sizes; (void)n_in; (void)out_size; (void)ws_size;
  const float* x  = (const float*)d_in[0];
  const float* Wq = (const float*)d_in[1];
  const float* bq = (const float*)d_in[2];
  const float* Wk = (const float*)d_in[3];
  const float* bk = (const float*)d_in[4];
  const float* Wv = (const float*)d_in[5];
  const float* bv = (const float*)d_in[6];

  char* ws = (char*)d_ws;
  f16* xh  = (f16*)ws; ws += (size_t)M_ * H_ * 2;          // 16 MiB
  f16* Wh  = (f16*)ws; ws += (size_t)3 * H_ * H_ * 2;      // 6 MiB
  f16* qkv = (f16*)ws; ws += (size_t)2 * M_ * H_ * 2;      // 32 MiB (q, k)
  f16* vT  = (f16*)ws; ws += (size_t)B_ * H_ * S_ * 2;     // 16 MiB
  f16* sc  = (f16*)ws; ws += (size_t)B_ * S_ * S_ * 2;     // 32 MiB (scores, then attn in-place)

  // 1) x, Wq/Wk/Wv -> fp16 in one launch
  downconvert_all<<<M_ * H_ / 1024 + 3 * H_ * H_ / 1024, 256, 0, stream>>>(
      x, Wq, Wk, Wv, xh, Wh);

  // 2) fused QKV projection + bias + quantize; V written transposed
  qkv_gemm<<<dim3(64, 24), 256, 0, stream>>>(xh, Wh, bq, bk, bv, qkv, vT);

  // 3) scores = quantize(q @ k^T / 32), per batch
  gemm_nt<1><<<dim3(16, 16, 4), 256, 0, stream>>>(
      qkv, qkv + (size_t)M_ * H_, sc, H_, H_, S_, H_,
      (long)S_ * H_, (long)S_ * H_, (long)S_ * S_, 0.03125f);

  // 4) attn = quantize(softmax(scores)) in-place — wave-per-row, no barriers
  softmax_w<<<M_ / 4, 256, 0, stream>>>(sc);

  // 5) out = attn @ vT^T  (fp32 epilogue straight to d_out)
  gemm_nt<0><<<dim3(16, 8, 4), 256, 0, stream>>>(
      sc, vT, d_out, S_, S_, H_, S_,
      (long)S_ * S_, (long)H_ * S_, (long)S_ * H_, 1.0f);
}

// Round 8
// 246.898 us; speedup vs baseline: 1.0233x; 1.0233x over previous
//
#include <hip/hip_runtime.h>
#include <hip/hip_fp16.h>

#define B_ 4
#define S_ 2048
#define H_ 1024
#define M_ (B_ * S_)  // 8192 flattened rows of x / q / k / v

typedef _Float16 f16;
typedef _Float16 f16x8 __attribute__((ext_vector_type(8)));
typedef _Float16 f16x4 __attribute__((ext_vector_type(4)));
typedef float f32x4 __attribute__((ext_vector_type(4)));

typedef __attribute__((address_space(3))) unsigned int* lds_u32p;
typedef const __attribute__((address_space(1))) unsigned int* gbl_u32p;

// async global->LDS, 16B per lane; LDS dest is wave-uniform base + lane*16
__device__ __forceinline__ void stage16(const f16* g, f16* l) {
  __builtin_amdgcn_global_load_lds((gbl_u32p)g, (lds_u32p)l, 16, 0, 0);
}

// ---------------------------------------------------------------------------
// One launch: x (8192 blocks) then Wq/Wk/Wv (1024 blocks each) -> fp16 RNE.
__global__ __launch_bounds__(256) void downconvert_all(
    const float* __restrict__ x, const float* __restrict__ W0,
    const float* __restrict__ W1, const float* __restrict__ W2,
    f16* __restrict__ xh, f16* __restrict__ Wh) {
  const int b = blockIdx.x;
  const float* src;
  f16* dst;
  long i;
  if (b < M_ * H_ / 1024) {  // 8192 x-blocks
    src = x; dst = xh;
    i = (long)b * 256 + threadIdx.x;
  } else {
    const int wb = b - M_ * H_ / 1024;
    const int sel = wb >> 10;               // 1024 blocks per W
    src = sel == 0 ? W0 : (sel == 1 ? W1 : W2);
    dst = Wh + (long)sel * H_ * H_;
    i = (long)(wb & 1023) * 256 + threadIdx.x;
  }
  f32x4 v = ((const f32x4*)src)[i];
  f16x4 h;
#pragma unroll
  for (int c = 0; c < 4; c++) h[c] = (f16)v[c];
  ((f16x4*)dst)[i] = h;
}

// ---------------------------------------------------------------------------
// Fused QKV projection — round-0 structure VERBATIM, NO swizzle.
// A/B evidence (r0=61.5 / r6-swz=~71 / r7=63.2): swizzle HURTS this kernel
// (weight-panel L2 reuse makes it stage-latency-bound; conflicts are hidden).
// NT GEMM, 128x128 tile, BK=64 as two BK=32 sub-chunks per barrier.
// sel==2 (V) is written TRANSPOSED to vT[b][h][t].
__global__ __launch_bounds__(256, 2)
void qkv_gemm(const f16* __restrict__ xh, const f16* __restrict__ Wh,
              const float* __restrict__ bq, const float* __restrict__ bk,
              const float* __restrict__ bv, f16* __restrict__ qkv,
              f16* __restrict__ vT) {
  __shared__ __align__(16) f16 As[2 * 128 * 32];  // [chunk0 | chunk1]
  __shared__ __align__(16) f16 Bs[2 * 128 * 32];
  const int t = threadIdx.x;
  const int wave = t >> 6, lane = t & 63;
  const int quad = lane >> 4, l16 = lane & 15;
  const int wm = (wave & 1) * 64, wn = (wave >> 1) * 64;
  const int sel = blockIdx.y >> 3;             // 0=q 1=k 2=v
  const int ntile = (blockIdx.y & 7) * 128;
  const int mtile = blockIdx.x * 128;

  const f16* Ab = xh + (long)mtile * H_;
  const f16* Bb = Wh + (long)sel * H_ * H_ + (long)ntile * H_;

  const int r0 = t >> 2;        // staging row 0..63
  const int c8 = (t & 3) * 8;   // staging col (halfs)

  f32x4 acc[4][4] = {};

  for (int k0 = 0; k0 < H_; k0 += 64) {
    __syncthreads();
    stage16(Ab + (long)r0 * H_ + k0 + c8,             As + t * 8);
    stage16(Ab + (long)(r0 + 64) * H_ + k0 + c8,      As + 2048 + t * 8);
    stage16(Ab + (long)r0 * H_ + k0 + 32 + c8,        As + 4096 + t * 8);
    stage16(Ab + (long)(r0 + 64) * H_ + k0 + 32 + c8, As + 6144 + t * 8);
    stage16(Bb + (long)r0 * H_ + k0 + c8,             Bs + t * 8);
    stage16(Bb + (long)(r0 + 64) * H_ + k0 + c8,      Bs + 2048 + t * 8);
    stage16(Bb + (long)r0 * H_ + k0 + 32 + c8,        Bs + 4096 + t * 8);
    stage16(Bb + (long)(r0 + 64) * H_ + k0 + 32 + c8, Bs + 6144 + t * 8);
    __syncthreads();
#pragma unroll
    for (int kk = 0; kk < 2; kk++) {
      f16x8 ah[4], bh[4];
#pragma unroll
      for (int i = 0; i < 4; i++) {
        ah[i] = *(const f16x8*)&As[kk * 4096 + (wm + i * 16 + l16) * 32 + quad * 8];
        bh[i] = *(const f16x8*)&Bs[kk * 4096 + (wn + i * 16 + l16) * 32 + quad * 8];
      }
#pragma unroll
      for (int i = 0; i < 4; i++)
#pragma unroll
        for (int j = 0; j < 4; j++)
          acc[i][j] = __builtin_amdgcn_mfma_f32_16x16x32_f16(ah[i], bh[j], acc[i][j], 0, 0, 0);
    }
  }

  const float* bias = sel == 0 ? bq : (sel == 1 ? bk : bv);
  if (sel == 2) {
    // V transposed: vT[(b*H + n)*S + t_pos], b = m>>11, t_pos = m&2047.
#pragma unroll
    for (int j = 0; j < 4; j++) {
      int n = ntile + wn + j * 16 + l16;
      float bb = bias[n];
#pragma unroll
      for (int i = 0; i < 4; i++) {
        int m = mtile + wm + i * 16 + quad * 4;
        f16x4 pack;
#pragma unroll
        for (int r = 0; r < 4; r++) pack[r] = (f16)(acc[i][j][r] + bb);
        *(f16x4*)&vT[((long)(m >> 11) * H_ + n) * S_ + (m & 2047)] = pack;
      }
    }
  } else {
    f16* out = qkv + (long)sel * M_ * H_;
#pragma unroll
    for (int j = 0; j < 4; j++) {
      int n = ntile + wn + j * 16 + l16;
      float bb = bias[n];
#pragma unroll
      for (int i = 0; i < 4; i++) {
        int m = mtile + wm + i * 16 + quad * 4;
#pragma unroll
        for (int r = 0; r < 4; r++)
          out[(long)(m + r) * H_ + n] = (f16)(acc[i][j][r] + bb);
      }
    }
  }
}

// ---------------------------------------------------------------------------
// Generic batched NT fp16 GEMM — round-0 structure + chunk-XOR swizzle.
// A/B evidence (r6 non-qkv 172.7 vs r7 189.5 with softmax held fixed):
// swizzle HELPS here (~17us across scores+PV) — activations have no
// weight-panel L2 reuse, so the LDS-read conflicts were exposed.
// Swizzle: 16B chunk c of row r holds global chunk c ^ ((r>>1)&3); applied
// on the global SOURCE of stage16 (LDS dest linear) and on ds_read address.
// C[z][m][n] = alpha * sum_k A[z][m][k]*B[z][n][k]
template <int OUT_F16>
__global__ __launch_bounds__(256, 2)
void gemm_nt(const f16* __restrict__ A, const f16* __restrict__ Bm,
             void* __restrict__ C, int lda, int ldb, int ldc, int K,
             long sA, long sB, long sC, float alpha) {
  __shared__ __align__(16) f16 As[2 * 128 * 32];
  __shared__ __align__(16) f16 Bs[2 * 128 * 32];
  const int t = threadIdx.x;
  const int wave = t >> 6, lane = t & 63;
  const int quad = lane >> 4, l16 = lane & 15;
  const int wm = (wave & 1) * 64, wn = (wave >> 1) * 64;
  const f16* Ab = A + blockIdx.z * sA + (long)blockIdx.x * 128 * lda;
  const f16* Bb = Bm + blockIdx.z * sB + (long)blockIdx.y * 128 * ldb;
  const int r0 = t >> 2;
  const int c8 = ((t & 3) ^ ((r0 >> 1) & 3)) * 8;    // pre-swizzled source
  const int swz8 = (quad ^ ((l16 >> 1) & 3)) * 8;    // swizzled ds_read
  f32x4 acc[4][4] = {};
  for (int k0 = 0; k0 < K; k0 += 64) {
    __syncthreads();
    stage16(Ab + (long)r0 * lda + k0 + c8,             As + t * 8);
    stage16(Ab + (long)(r0 + 64) * lda + k0 + c8,      As + 2048 + t * 8);
    stage16(Ab + (long)r0 * lda + k0 + 32 + c8,        As + 4096 + t * 8);
    stage16(Ab + (long)(r0 + 64) * lda + k0 + 32 + c8, As + 6144 + t * 8);
    stage16(Bb + (long)r0 * ldb + k0 + c8,             Bs + t * 8);
    stage16(Bb + (long)(r0 + 64) * ldb + k0 + c8,      Bs + 2048 + t * 8);
    stage16(Bb + (long)r0 * ldb + k0 + 32 + c8,        Bs + 4096 + t * 8);
    stage16(Bb + (long)(r0 + 64) * ldb + k0 + 32 + c8, Bs + 6144 + t * 8);
    __syncthreads();
#pragma unroll
    for (int kk = 0; kk < 2; kk++) {
      f16x8 af[4], bf[4];
#pragma unroll
      for (int i = 0; i < 4; i++) {
        af[i] = *(const f16x8*)&As[kk * 4096 + (wm + i * 16 + l16) * 32 + swz8];
        bf[i] = *(const f16x8*)&Bs[kk * 4096 + (wn + i * 16 + l16) * 32 + swz8];
      }
#pragma unroll
      for (int i = 0; i < 4; i++)
#pragma unroll
        for (int j = 0; j < 4; j++)
          acc[i][j] = __builtin_amdgcn_mfma_f32_16x16x32_f16(af[i], bf[j], acc[i][j], 0, 0, 0);
    }
  }
  const long mb = (long)blockIdx.x * 128 + wm;
  const long nb = (long)blockIdx.y * 128 + wn;
#pragma unroll
  for (int i = 0; i < 4; i++)
#pragma unroll
    for (int j = 0; j < 4; j++) {
      long m = mb + i * 16 + quad * 4;
      long n = nb + j * 16 + l16;
#pragma unroll
      for (int r = 0; r < 4; r++) {
        float v = acc[i][j][r] * alpha;
        if (OUT_F16)
          ((f16*)C)[blockIdx.z * sC + (m + r) * ldc + n] = (f16)v;
        else
          ((float*)C)[blockIdx.z * sC + (m + r) * ldc + n] = v;
      }
    }
}

// ---------------------------------------------------------------------------
// Wave-per-row softmax + fp16 quantize: 4 rows per 256-thread block.
// No LDS, no __syncthreads, pure shfl reductions; 64B/lane vectorized I/O.
// (r7 lesson: ~neutral vs block version — kept for simplicity.)
__global__ __launch_bounds__(256) void softmax_w(f16* __restrict__ sc) {
  const int wave = threadIdx.x >> 6, lane = threadIdx.x & 63;
  const long row = (long)blockIdx.x * 4 + wave;
  f16* p = sc + row * S_;
  f16x8 v[4];
#pragma unroll
  for (int i = 0; i < 4; ++i) v[i] = ((const f16x8*)p)[i * 64 + lane];
  float f[32];
  float m = -3.0e38f;
#pragma unroll
  for (int i = 0; i < 4; ++i)
#pragma unroll
    for (int c = 0; c < 8; ++c) {
      float x = (float)v[i][c];
      f[i * 8 + c] = x;
      m = fmaxf(m, x);
    }
#pragma unroll
  for (int o = 32; o > 0; o >>= 1) m = fmaxf(m, __shfl_xor(m, o));
  float s = 0.f;
#pragma unroll
  for (int i = 0; i < 32; ++i) { f[i] = __expf(f[i] - m); s += f[i]; }
#pragma unroll
  for (int o = 32; o > 0; o >>= 1) s += __shfl_xor(s, o);
  const float inv = 1.0f / s;
#pragma unroll
  for (int i = 0; i < 4; ++i) {
    f16x8 ov;
#pragma unroll
    for (int c = 0; c < 8; ++c) ov[c] = (f16)(f[i * 8 + c] * inv);
    ((f16x8*)p)[i * 64 + lane] = ov;
  }
}

// ---------------------------------------------------------------------------
extern "C" void kernel_launch(void* const* d_in, const int* in_sizes, int n_in,
                              void* d_out, int out_size, void* d_ws, size_t ws_size,
                              hipStream_t stream) {
  (void)in_sizes; (void)n_in; (void)out_size; (void)ws_size;
  const float* x  = (const float*)d_in[0];
  const float* Wq = (const float*)d_in[1];
  const float* bq = (const float*)d_in[2];
  const float* Wk = (const float*)d_in[3];
  const float* bk = (const float*)d_in[4];
  const float* Wv = (const float*)d_in[5];
  const float* bv = (const float*)d_in[6];

  char* ws = (char*)d_ws;
  f16* xh  = (f16*)ws; ws += (size_t)M_ * H_ * 2;          // 16 MiB
  f16* Wh  = (f16*)ws; ws += (size_t)3 * H_ * H_ * 2;      // 6 MiB
  f16* qkv = (f16*)ws; ws += (size_t)2 * M_ * H_ * 2;      // 32 MiB (q, k)
  f16* vT  = (f16*)ws; ws += (size_t)B_ * H_ * S_ * 2;     // 16 MiB
  f16* sc  = (f16*)ws; ws += (size_t)B_ * S_ * S_ * 2;     // 32 MiB (scores, then attn in-place)

  // 1) x, Wq/Wk/Wv -> fp16 in one launch
  downconvert_all<<<M_ * H_ / 1024 + 3 * H_ * H_ / 1024, 256, 0, stream>>>(
      x, Wq, Wk, Wv, xh, Wh);

  // 2) fused QKV projection + bias + quantize; V written transposed
  qkv_gemm<<<dim3(64, 24), 256, 0, stream>>>(xh, Wh, bq, bk, bv, qkv, vT);

  // 3) scores = quantize(q @ k^T / 32), per batch — swizzled gemm_nt
  gemm_nt<1><<<dim3(16, 16, 4), 256, 0, stream>>>(
      qkv, qkv + (size_t)M_ * H_, sc, H_, H_, S_, H_,
      (long)S_ * H_, (long)S_ * H_, (long)S_ * S_, 0.03125f);

  // 4) attn = quantize(softmax(scores)) in-place — wave-per-row
  softmax_w<<<M_ / 4, 256, 0, stream>>>(sc);

  // 5) out = attn @ vT^T (fp32 straight to d_out) — swizzled gemm_nt
  gemm_nt<0><<<dim3(16, 8, 4), 256, 0, stream>>>(
      sc, vT, d_out, S_, S_, H_, S_,
      (long)S_ * S_, (long)H_ * S_, (long)S_ * H_, 1.0f);
}